// Round 4
// baseline (241.070 us; speedup 1.0000x reference)
//
#include <hip/hip_runtime.h>

// PAM module: B=4, C=512, N=4096, Cq=64.
// prep_kernel: W -> bf16 (Wq/Wk split hi/lo) once.
// proj_kernel: q,k,v = W@x + b (split-bf16 MFMA). q,k transposed+split
//   [B][N][64] hi/lo bf16; v bf16 [B][C][N].
// attn_kernel: flash attention, 64-row i-panels (grid 256), 8 waves, j-tile
//   256 (16 iters). Register-resident partial softmax per wave (each wave
//   owns a 32-j sub-range for all i); cross-wave merge via tiny Mpart/Lpart
//   LDS; m/l tracked per-lane in registers; E never goes to LDS. P written
//   [i][j] bf16 (XOR-swizzled) and read directly as PV B-frags. K prefetch
//   1 tile ahead, V slice-pipelined, lgkm-only barriers (2 per iter).

typedef float          f32x4  __attribute__((ext_vector_type(4)));
typedef short          bf16x8 __attribute__((ext_vector_type(8)));
typedef unsigned short u16x4  __attribute__((ext_vector_type(4)));

#define MFMA16(a, b, c) __builtin_amdgcn_mfma_f32_16x16x32_bf16((a), (b), (c), 0, 0, 0)

__device__ __forceinline__ unsigned short bf16_rne(float f) {
    unsigned u = __builtin_bit_cast(unsigned, f);
    u += 0x7FFFu + ((u >> 16) & 1u);
    return (unsigned short)(u >> 16);
}
__device__ __forceinline__ float bf16_f(unsigned short h) {
    unsigned u = (unsigned)h << 16;
    return __builtin_bit_cast(float, u);
}

// lgkm-only drain + raw barrier: keeps global-load prefetches (vmcnt) in
// flight across the barrier (a __syncthreads would drain vmcnt(0)).
#define BARRIER_LGKM() do {                                   \
    asm volatile("s_waitcnt lgkmcnt(0)" ::: "memory");        \
    __builtin_amdgcn_s_barrier();                             \
    asm volatile("" ::: "memory");                            \
} while (0)

constexpr int BB = 4, CCH = 512, NS = 4096;

// ---------------------------------------------------------------------------
// Prep: convert weights to bf16. Grid 256 x 256 threads.
// ---------------------------------------------------------------------------
__global__ void prep_kernel(
    const float* __restrict__ Wq, const float* __restrict__ Wk,
    const float* __restrict__ Wv,
    unsigned short* __restrict__ Wqh, unsigned short* __restrict__ Wql,
    unsigned short* __restrict__ Wkh, unsigned short* __restrict__ Wkl,
    unsigned short* __restrict__ Wvb)
{
    const int idx = blockIdx.x * 256 + threadIdx.x; // 0..65535
    {
        f32x4 v = *(const f32x4*)&Wv[(size_t)idx * 4];
        u16x4 o;
#pragma unroll
        for (int e = 0; e < 4; ++e) o[e] = bf16_rne(v[e]);
        *(u16x4*)&Wvb[(size_t)idx * 4] = o;
    }
    if (idx < 8192) {
        f32x4 q = *(const f32x4*)&Wq[(size_t)idx * 4];
        f32x4 k = *(const f32x4*)&Wk[(size_t)idx * 4];
        u16x4 qh, ql, kh, kl;
#pragma unroll
        for (int e = 0; e < 4; ++e) {
            unsigned short h = bf16_rne(q[e]);
            qh[e] = h; ql[e] = bf16_rne(q[e] - bf16_f(h));
            h = bf16_rne(k[e]);
            kh[e] = h; kl[e] = bf16_rne(k[e] - bf16_f(h));
        }
        *(u16x4*)&Wqh[(size_t)idx * 4] = qh;
        *(u16x4*)&Wql[(size_t)idx * 4] = ql;
        *(u16x4*)&Wkh[(size_t)idx * 4] = kh;
        *(u16x4*)&Wkl[(size_t)idx * 4] = kl;
    }
}

// ---------------------------------------------------------------------------
// Projection. Grid: 256 = b(4) x n-tile(64 of 64 cols). Block: 512 thr.
// ---------------------------------------------------------------------------
__global__ __launch_bounds__(512, 2) void proj_kernel(
    const float* __restrict__ x,
    const unsigned short* __restrict__ Wqh, const unsigned short* __restrict__ Wql,
    const unsigned short* __restrict__ Wkh, const unsigned short* __restrict__ Wkl,
    const unsigned short* __restrict__ Wvb,
    const float* __restrict__ bq, const float* __restrict__ bk,
    const float* __restrict__ bv,
    unsigned short* __restrict__ qhi, unsigned short* __restrict__ qlo,
    unsigned short* __restrict__ khi, unsigned short* __restrict__ klo,
    unsigned short* __restrict__ vws)
{
    const int t = threadIdx.x, lane = t & 63, w = t >> 6;
    const int l15 = lane & 15, l4 = lane >> 4;
    const int b  = blockIdx.x >> 6;
    const int n0 = (blockIdx.x & 63) * 64;
    const float* xb = x + (size_t)b * CCH * NS;

    __shared__ unsigned short xh[64][40];
    __shared__ unsigned short xl[64][40];

    f32x4 accv[4][4];
    f32x4 accq[4];
#pragma unroll
    for (int a = 0; a < 4; ++a)
#pragma unroll
        for (int n = 0; n < 4; ++n)
#pragma unroll
            for (int r = 0; r < 4; ++r) accv[a][n][r] = 0.f;
#pragma unroll
    for (int n = 0; n < 4; ++n)
#pragma unroll
        for (int r = 0; r < 4; ++r) accq[n][r] = 0.f;

    const unsigned short* Wh = (w < 4) ? Wqh : Wkh;
    const unsigned short* Wl = (w < 4) ? Wql : Wkl;
    const int oq0 = (w & 3) * 16;
    const int stg_c = t >> 4;
    const int stg_n = (t & 15) * 4;

    f32x4 xv = *(const f32x4*)&xb[(size_t)stg_c * NS + n0 + stg_n];

    for (int cc = 0; cc < 16; ++cc) {
#pragma unroll
        for (int u = 0; u < 4; ++u) {
            unsigned short h = bf16_rne(xv[u]);
            xh[stg_n + u][stg_c] = h;
            xl[stg_n + u][stg_c] = bf16_rne(xv[u] - bf16_f(h));
        }
        BARRIER_LGKM();

        bf16x8 bh[4], bl[4];
#pragma unroll
        for (int nf = 0; nf < 4; ++nf) {
            bh[nf] = *(const bf16x8*)&xh[nf * 16 + l15][l4 * 8];
            bl[nf] = *(const bf16x8*)&xl[nf * 16 + l15][l4 * 8];
        }
        const int c8 = cc * 32 + l4 * 8;

        const int ccn = (cc + 1) & 15;
        xv = *(const f32x4*)&xb[(size_t)(ccn * 32 + stg_c) * NS + n0 + stg_n];

#pragma unroll
        for (int af = 0; af < 4; ++af) {
            bf16x8 ah = *(const bf16x8*)&Wvb[(size_t)(w * 64 + af * 16 + l15) * CCH + c8];
#pragma unroll
            for (int nf = 0; nf < 4; ++nf)
                accv[af][nf] = MFMA16(ah, bh[nf], accv[af][nf]);
        }
        {
            bf16x8 ah = *(const bf16x8*)&Wh[(size_t)(oq0 + l15) * CCH + c8];
            bf16x8 al = *(const bf16x8*)&Wl[(size_t)(oq0 + l15) * CCH + c8];
#pragma unroll
            for (int nf = 0; nf < 4; ++nf) {
                accq[nf] = MFMA16(ah, bh[nf], accq[nf]);
                accq[nf] = MFMA16(ah, bl[nf], accq[nf]);
                accq[nf] = MFMA16(al, bh[nf], accq[nf]);
            }
        }
        BARRIER_LGKM();
    }

#pragma unroll
    for (int af = 0; af < 4; ++af) {
#pragma unroll
        for (int r = 0; r < 4; ++r) {
            const int o = w * 64 + af * 16 + l4 * 4 + r;
            const float bias = bv[o];
#pragma unroll
            for (int nf = 0; nf < 4; ++nf) {
                const int n = n0 + nf * 16 + l15;
                vws[(size_t)(b * CCH + o) * NS + n] = bf16_rne(accv[af][nf][r] + bias);
            }
        }
    }
    {
        unsigned short* hiT = (w < 4) ? qhi : khi;
        unsigned short* loT = (w < 4) ? qlo : klo;
        const float* bqk = (w < 4) ? bq : bk;
        float bias[4];
#pragma unroll
        for (int r = 0; r < 4; ++r) bias[r] = bqk[oq0 + l4 * 4 + r];
#pragma unroll
        for (int nf = 0; nf < 4; ++nf) {
            const int n = n0 + nf * 16 + l15;
            u16x4 hv, lv;
#pragma unroll
            for (int r = 0; r < 4; ++r) {
                float val = accq[nf][r] + bias[r];
                unsigned short h = bf16_rne(val);
                hv[r] = h;
                lv[r] = bf16_rne(val - bf16_f(h));
            }
            const size_t base = ((size_t)b * NS + n) * 64 + oq0 + l4 * 4;
            *(u16x4*)&hiT[base] = hv;
            *(u16x4*)&loT[base] = lv;
        }
    }
}

// ---------------------------------------------------------------------------
// Flash attention. Grid: 256 = b(4) x i-panel(64 rows). 512 thr = 8 waves.
// j-tile 256 = 8 waves x 32-j sub-ranges. Register softmax + LDS merge.
// ---------------------------------------------------------------------------
__global__ __launch_bounds__(512, 2) void attn_kernel(
    const float* __restrict__ x, const float* __restrict__ gamma,
    const unsigned short* __restrict__ qhi, const unsigned short* __restrict__ qlo,
    const unsigned short* __restrict__ khi, const unsigned short* __restrict__ klo,
    const unsigned short* __restrict__ vws, float* __restrict__ out)
{
    const int t = threadIdx.x, lane = t & 63, w = t >> 6;
    const int l15 = lane & 15, l4 = lane >> 4;
    const int b  = blockIdx.x >> 6;
    const int i0 = (blockIdx.x & 63) * 64;

    __shared__ unsigned short Qlds[2][64][64];   // swizzled: [(g ^ (i&7))*8]
    __shared__ unsigned short Plds[2][64][256];  // [i][j] bf16, 16B-granule XOR by (i&7)
    __shared__ float Mpart[16][4][8];            // [l15][ifr][wave]
    __shared__ float Lpart[16][4][8];

    // ---- prologue: stage Q (swizzled) ----
    {
        const int qi = t >> 3, g0 = t & 7;
        const size_t ga = ((size_t)(b * NS + i0 + qi)) * 64 + g0 * 8;
        bf16x8 qh8 = *(const bf16x8*)&qhi[ga];
        bf16x8 ql8 = *(const bf16x8*)&qlo[ga];
        const int gs = (g0 ^ (qi & 7)) * 8;
        *(bf16x8*)&Qlds[0][qi][gs] = qh8;
        *(bf16x8*)&Qlds[1][qi][gs] = ql8;
    }

    f32x4 O[4][4]; // [af(c)][ifr(i)]
#pragma unroll
    for (int a = 0; a < 4; ++a)
#pragma unroll
        for (int f = 0; f < 4; ++f)
#pragma unroll
            for (int r = 0; r < 4; ++r) O[a][f][r] = 0.f;

    float m_run[4], l_run[4];
#pragma unroll
    for (int f = 0; f < 4; ++f) { m_run[f] = -1e30f; l_run[f] = 0.f; }

    const unsigned short* vb = vws + (size_t)b * CCH * NS;
    const size_t kbase = (size_t)b * NS * 64;

    // K(0) prefetch: rows j = 32w + jf*16 + l15
    bf16x8 kh[2][2], kl[2][2]; // [jf][ds]
#pragma unroll
    for (int jf = 0; jf < 2; ++jf) {
        const size_t kr = kbase + (size_t)(32 * w + jf * 16 + l15) * 64 + l4 * 8;
        kh[jf][0] = *(const bf16x8*)&khi[kr];  kh[jf][1] = *(const bf16x8*)&khi[kr + 32];
        kl[jf][0] = *(const bf16x8*)&klo[kr];  kl[jf][1] = *(const bf16x8*)&klo[kr + 32];
    }
    // V(tile0, slice0) prefetch
    bf16x8 va[2][4]; // [parity][af]
#pragma unroll
    for (int af = 0; af < 4; ++af)
        va[0][af] = *(const bf16x8*)&vb[(size_t)(w * 64 + af * 16 + l15) * NS + l4 * 8];

    BARRIER_LGKM(); // Q staged; K/V global loads remain in flight

    for (int jt = 0; jt < 16; ++jt) {
        const int buf = jt & 1;
        const int j0 = jt * 256;
        const int jn = ((jt + 1) & 15) * 256;

        // ---- QK: E[j=32w+jf*16+(l4*4+r)][i=ifr*16+l15], 3-term split ----
        f32x4 eacc[2][4]; // [jf][ifr]
#pragma unroll
        for (int jf = 0; jf < 2; ++jf)
#pragma unroll
            for (int f = 0; f < 4; ++f)
#pragma unroll
                for (int r = 0; r < 4; ++r) eacc[jf][f][r] = 0.f;
#pragma unroll
        for (int ds = 0; ds < 2; ++ds) {
            const int gq = ((ds * 4 + l4) ^ (l15 & 7)) * 8;
            bf16x8 qhf[4], qlf[4];
#pragma unroll
            for (int f = 0; f < 4; ++f) {
                qhf[f] = *(const bf16x8*)&Qlds[0][f * 16 + l15][gq];
                qlf[f] = *(const bf16x8*)&Qlds[1][f * 16 + l15][gq];
            }
#pragma unroll
            for (int jf = 0; jf < 2; ++jf)
#pragma unroll
                for (int f = 0; f < 4; ++f) {
                    eacc[jf][f] = MFMA16(kh[jf][ds], qhf[f], eacc[jf][f]);
                    eacc[jf][f] = MFMA16(kh[jf][ds], qlf[f], eacc[jf][f]);
                    eacc[jf][f] = MFMA16(kl[jf][ds], qhf[f], eacc[jf][f]);
                }
        }

        // ---- partial max over this wave's 32 j, per ifr ----
        float mp[4];
#pragma unroll
        for (int f = 0; f < 4; ++f) {
            float mx = fmaxf(fmaxf(eacc[0][f][0], eacc[0][f][1]),
                             fmaxf(eacc[0][f][2], eacc[0][f][3]));
            mx = fmaxf(mx, fmaxf(fmaxf(eacc[1][f][0], eacc[1][f][1]),
                                 fmaxf(eacc[1][f][2], eacc[1][f][3])));
            mx = fmaxf(mx, __shfl_xor(mx, 16));
            mx = fmaxf(mx, __shfl_xor(mx, 32));
            mp[f] = mx;
        }
        if (l4 == 0) {
#pragma unroll
            for (int f = 0; f < 4; ++f) Mpart[l15][f][w] = mp[f];
        }
        BARRIER_LGKM(); // #1 (max merge)

        // ---- global tile max, sc, exp+pack+P write, partial sums ----
        float mn[4], sc[4];
        bool need = false;
#pragma unroll
        for (int f = 0; f < 4; ++f) {
            f32x4 ma = *(const f32x4*)&Mpart[l15][f][0];
            f32x4 mb = *(const f32x4*)&Mpart[l15][f][4];
            float mt = fmaxf(fmaxf(fmaxf(ma[0], ma[1]), fmaxf(ma[2], ma[3])),
                             fmaxf(fmaxf(mb[0], mb[1]), fmaxf(mb[2], mb[3])));
            mn[f] = fmaxf(m_run[f], mt);
            need = need || (mn[f] > m_run[f]);
            sc[f] = __expf(m_run[f] - mn[f]);
            m_run[f] = mn[f];
        }
        char* prow_base = (char*)&Plds[buf][0][0];
#pragma unroll
        for (int f = 0; f < 4; ++f) {
            float ls = 0.f;
            char* prow = prow_base + (size_t)(f * 16 + l15) * 512;
#pragma unroll
            for (int jf = 0; jf < 2; ++jf) {
                u16x4 pk;
#pragma unroll
                for (int r = 0; r < 4; ++r) {
                    float p = __expf(eacc[jf][f][r] - mn[f]);
                    ls += p;
                    pk[r] = bf16_rne(p);
                }
                const int joff = (w * 64 + jf * 32 + l4 * 8) ^ ((l15 & 7) << 4);
                *(u16x4*)(prow + joff) = pk;
            }
            ls += __shfl_xor(ls, 16);
            ls += __shfl_xor(ls, 32);
            if (l4 == 0) Lpart[l15][f][w] = ls;
        }
        // K(t+1) prefetch (in flight across barriers)
#pragma unroll
        for (int jf = 0; jf < 2; ++jf) {
            const size_t kr = kbase + (size_t)(jn + 32 * w + jf * 16 + l15) * 64 + l4 * 8;
            kh[jf][0] = *(const bf16x8*)&khi[kr];  kh[jf][1] = *(const bf16x8*)&khi[kr + 32];
            kl[jf][0] = *(const bf16x8*)&klo[kr];  kl[jf][1] = *(const bf16x8*)&klo[kr + 32];
        }
        BARRIER_LGKM(); // #2 (P publish)

        // ---- l merge, O rescale ----
#pragma unroll
        for (int f = 0; f < 4; ++f) {
            f32x4 la = *(const f32x4*)&Lpart[l15][f][0];
            f32x4 lb = *(const f32x4*)&Lpart[l15][f][4];
            float ls8 = ((la[0] + la[1]) + (la[2] + la[3])) +
                        ((lb[0] + lb[1]) + (lb[2] + lb[3]));
            l_run[f] = l_run[f] * sc[f] + ls8;
        }
        if (__any(need)) {
#pragma unroll
            for (int a = 0; a < 4; ++a)
#pragma unroll
                for (int f = 0; f < 4; ++f)
#pragma unroll
                    for (int r = 0; r < 4; ++r) O[a][f][r] *= sc[f];
        }

        // ---- PV: 8 slices of 32 j, V ping-pong prefetch ----
        char* pbuf = (char*)&Plds[buf][0][0];
#pragma unroll
        for (int s = 0; s < 8; ++s) {
            const int par = s & 1, nxt = par ^ 1;
            const int joff_next = (s < 7) ? (j0 + (s + 1) * 32) : jn;
#pragma unroll
            for (int af = 0; af < 4; ++af)
                va[nxt][af] = *(const bf16x8*)&vb[(size_t)(w * 64 + af * 16 + l15) * NS + joff_next + l4 * 8];
            bf16x8 pb[4];
#pragma unroll
            for (int f = 0; f < 4; ++f)
                pb[f] = *(const bf16x8*)(pbuf + (size_t)(f * 16 + l15) * 512 +
                                         ((s * 64 + l4 * 16) ^ ((l15 & 7) << 4)));
            __builtin_amdgcn_s_setprio(1);
#pragma unroll
            for (int af = 0; af < 4; ++af)
#pragma unroll
                for (int f = 0; f < 4; ++f)
                    O[af][f] = MFMA16(va[par][af], pb[f], O[af][f]);
            __builtin_amdgcn_s_setprio(0);
        }
    }

    // ---- epilogue: out = gamma * O/l + x ----
    const float g = gamma[0];
    const float* xb = x + (size_t)b * CCH * NS;
    float linv[4];
#pragma unroll
    for (int f = 0; f < 4; ++f) linv[f] = 1.f / l_run[f];
#pragma unroll
    for (int a = 0; a < 4; ++a) {
#pragma unroll
        for (int r = 0; r < 4; ++r) {
            const int c = w * 64 + a * 16 + l4 * 4 + r;
#pragma unroll
            for (int f = 0; f < 4; ++f) {
                const int i = i0 + f * 16 + l15;
                out[(size_t)(b * CCH + c) * NS + i] =
                    g * (O[a][f][r] * linv[f]) + xb[(size_t)c * NS + i];
            }
        }
    }
}

// ---------------------------------------------------------------------------
extern "C" void kernel_launch(void* const* d_in, const int* in_sizes, int n_in,
                              void* d_out, int out_size, void* d_ws, size_t ws_size,
                              hipStream_t stream)
{
    const float* x     = (const float*)d_in[0];
    const float* Wq    = (const float*)d_in[1];
    const float* bq    = (const float*)d_in[2];
    const float* Wk    = (const float*)d_in[3];
    const float* bk    = (const float*)d_in[4];
    const float* Wv    = (const float*)d_in[5];
    const float* bv    = (const float*)d_in[6];
    const float* gamma = (const float*)d_in[7];
    float* out = (float*)d_out;

    const size_t QK_ELEMS = (size_t)BB * NS * 64;   // 1,048,576
    unsigned short* qhi = (unsigned short*)d_ws;
    unsigned short* qlo = qhi + QK_ELEMS;
    unsigned short* khi = qlo + QK_ELEMS;
    unsigned short* klo = khi + QK_ELEMS;
    unsigned short* v   = klo + QK_ELEMS;           // [4][512][4096] = 16 MB
    unsigned short* Wvb = v   + (size_t)BB * CCH * NS;
    unsigned short* Wqh = Wvb + (size_t)CCH * CCH;
    unsigned short* Wql = Wqh + 64 * CCH;
    unsigned short* Wkh = Wql + 64 * CCH;
    unsigned short* Wkl = Wkh + 64 * CCH;

    prep_kernel<<<256, 256, 0, stream>>>(Wq, Wk, Wv, Wqh, Wql, Wkh, Wkl, Wvb);
    proj_kernel<<<256, 512, 0, stream>>>(x, Wqh, Wql, Wkh, Wkl, Wvb,
                                         bq, bk, bv, qhi, qlo, khi, klo, v);
    attn_kernel<<<256, 512, 0, stream>>>(x, gamma, qhi, qlo, khi, klo, v, out);
}